// Round 2
// baseline (129.605 us; speedup 1.0000x reference)
//
#include <hip/hip_runtime.h>
#include <math.h>

#define NB 8192
#define DK 256
#define BM 128
#define BK 64
#define NTILE 64            // NB/BM
#define NBLK (NTILE*(NTILE+1)/2)   // 2080 upper-triangular tiles

typedef __bf16 bf16x8 __attribute__((ext_vector_type(8)));
typedef float f32x4 __attribute__((ext_vector_type(4)));

__device__ inline unsigned short f2bf(float f) {
  unsigned u = __float_as_uint(f);
  u += 0x7fffu + ((u >> 16) & 1u);          // round-to-nearest-even
  return (unsigned short)(u >> 16);
}

__device__ inline void gld_lds16(const void* g, void* l) {
  __builtin_amdgcn_global_load_lds(
      (const __attribute__((address_space(1))) void*)g,
      (__attribute__((address_space(3))) void*)l, 16, 0, 0);
}

// ---------------- Kernel 1: L2-normalize rows, fp32 -> bf16; zero acc+ticket
__global__ __launch_bounds__(256) void normalize_kernel(
    const float* __restrict__ emb, unsigned short* __restrict__ ebf,
    float* __restrict__ acc, unsigned* __restrict__ ticket) {
  if (blockIdx.x == 0 && threadIdx.x == 0) { acc[0] = 0.0f; ticket[0] = 0u; }
  int wave = threadIdx.x >> 6;
  int lane = threadIdx.x & 63;
  int row = blockIdx.x * 4 + wave;                  // one wave per row
  const float4* src = reinterpret_cast<const float4*>(emb + (size_t)row * DK) + lane;
  float4 v = *src;
  float ss = v.x * v.x + v.y * v.y + v.z * v.z + v.w * v.w;
  #pragma unroll
  for (int m = 1; m < 64; m <<= 1) ss += __shfl_xor(ss, m, 64);
  float inv = 1.0f / sqrtf(ss);
  ushort4 o;
  o.x = f2bf(v.x * inv);
  o.y = f2bf(v.y * inv);
  o.z = f2bf(v.z * inv);
  o.w = f2bf(v.w * inv);
  *reinterpret_cast<ushort4*>(ebf + (size_t)row * DK + lane * 4) = o;
}

// ---------------- Kernel 2: sim tiles via bf16 MFMA, 2-phase double-buffered
// 1D triangular grid: block b -> (tr, tc) with tc >= tr. Off-diagonal doubled.
// Last block (atomic ticket) computes log1p and writes the output.
__global__ __launch_bounds__(256) void circle_gemm(
    const unsigned short* __restrict__ ebf, const int* __restrict__ labels,
    float* __restrict__ acc, unsigned* __restrict__ ticket,
    float* __restrict__ out) {
  // decode triangular tile index (uniform scalar loop, <=64 iters)
  int rem = blockIdx.x;
  int tr = 0;
  while (rem >= NTILE - tr) { rem -= NTILE - tr; ++tr; }
  int tc = tr + rem;

  __shared__ unsigned short As[2][BM * BK];          // 2 x 16 KB, swizzled
  __shared__ unsigned short Bs[2][BM * BK];          // 2 x 16 KB
  __shared__ int labR[BM], labC[BM];
  __shared__ float wsum[4];

  int tid = threadIdx.x;
  int lane = tid & 63;
  int wave = tid >> 6;
  int row0 = tr * BM, col0 = tc * BM;

  // stage one K-slab (A and B) into buffer bufi with st-style XOR swizzle:
  // LDS dest linear, global source pre-swizzled (m173 pattern)
  auto stage = [&](int k0, int bufi) {
    #pragma unroll
    for (int q = 0; q < 4; ++q) {
      int o = q * 4096 + tid * 16;                   // linear byte offset
      int r = o >> 7;                                // row (128B rows)
      int os = o ^ ((r & 7) << 4);                   // swizzled (same row)
      int kc = (os & 127) >> 1;                      // bf16 col within row
      gld_lds16(&ebf[(size_t)(row0 + r) * DK + k0 + kc], ((char*)As[bufi]) + o);
      gld_lds16(&ebf[(size_t)(col0 + r) * DK + k0 + kc], ((char*)Bs[bufi]) + o);
    }
  };

  stage(0, 0);                                       // prologue prefetch
  if (tid < 128) labR[tid] = labels[row0 + tid];
  else           labC[tid - 128] = labels[col0 + (tid - 128)];
  __syncthreads();                                   // drains vmcnt(0) too

  f32x4 accf[4][4] = {};                             // 64 fp32 accum / thread
  int wr = (wave >> 1) * 64;                         // wave's 64x64 sub-tile
  int wc = (wave & 1) * 64;
  int frow = lane & 15;
  int khi = (lane >> 4) << 3;                        // k-subgroup (8 elems)

  #pragma unroll
  for (int t = 0; t < DK / BK; ++t) {
    int curb = t & 1;
    if (t < DK / BK - 1) stage((t + 1) * BK, curb ^ 1);   // prefetch next slab

    #pragma unroll
    for (int kk = 0; kk < BK; kk += 32) {
      int kb = (kk + khi) * 2;                       // byte offset of 8-k group
      bf16x8 a[4], b[4];
      #pragma unroll
      for (int m = 0; m < 4; ++m) {
        int r = wr + m * 16 + frow;
        int ob = ((r << 7) + kb) ^ ((r & 7) << 4);   // swizzled read
        a[m] = *reinterpret_cast<bf16x8*>(((char*)As[curb]) + ob);
      }
      #pragma unroll
      for (int n = 0; n < 4; ++n) {
        int r = wc + n * 16 + frow;
        int ob = ((r << 7) + kb) ^ ((r & 7) << 4);
        b[n] = *reinterpret_cast<bf16x8*>(((char*)Bs[curb]) + ob);
      }
      #pragma unroll
      for (int m = 0; m < 4; ++m)
        #pragma unroll
        for (int n = 0; n < 4; ++n)
          accf[m][n] = __builtin_amdgcn_mfma_f32_16x16x32_bf16(a[m], b[n], accf[m][n], 0, 0, 0);
    }
    __syncthreads();   // one barrier/K-step: drains stage vmem (hidden under compute)
  }

  // epilogue: circle-loss terms, one exp per element
  // C/D layout (verified m89/m91): col = lane&15, row = (lane>>4)*4 + reg
  float lsum = 0.0f;
  int rbase = wr + ((lane >> 4) << 2);
  int cbase = wc + (lane & 15);
  #pragma unroll
  for (int m = 0; m < 4; ++m) {
    #pragma unroll
    for (int n = 0; n < 4; ++n) {
      int lc = labC[cbase + n * 16];
      #pragma unroll
      for (int e = 0; e < 4; ++e) {
        float s = accf[m][n][e];
        bool pos = (labR[rbase + m * 16 + e] == lc);
        float relu = pos ? fmaxf(s - 0.75f, 0.0f) : fmaxf(0.25f - s, 0.0f);
        float arg  = pos ? (2.5f - 2.0f * s)      : (2.0f * s + 0.5f);
        lsum += relu * __expf(arg);
      }
    }
  }
  #pragma unroll
  for (int m = 32; m; m >>= 1) lsum += __shfl_xor(lsum, m, 64);
  if (lane == 0) wsum[wave] = lsum;
  __syncthreads();
  if (tid == 0) {
    float s = wsum[0] + wsum[1] + wsum[2] + wsum[3];
    if (tc != tr) s *= 2.0f;                         // symmetry doubling
    atomicAdd(acc, s);
    __threadfence();
    unsigned my = atomicAdd(ticket, 1u);
    if (my == NBLK - 1) {                            // last block finalizes
      __threadfence();
      float v = atomicAdd(acc, 0.0f);                // coherent read
      out[0] = logf(1.0f + v);
    }
  }
}

extern "C" void kernel_launch(void* const* d_in, const int* in_sizes, int n_in,
                              void* d_out, int out_size, void* d_ws, size_t ws_size,
                              hipStream_t stream) {
  const float* emb = (const float*)d_in[0];
  const int* labels = (const int*)d_in[1];
  float* out = (float*)d_out;
  unsigned short* ebf = (unsigned short*)d_ws;                       // 4 MB bf16 E
  float* acc = (float*)((char*)d_ws + (size_t)NB * DK * 2);
  unsigned* ticket = (unsigned*)((char*)d_ws + (size_t)NB * DK * 2 + 4);

  hipLaunchKernelGGL(normalize_kernel, dim3(NB / 4), dim3(256), 0, stream,
                     emb, ebf, acc, ticket);
  hipLaunchKernelGGL(circle_gemm, dim3(NBLK), dim3(256), 0, stream,
                     ebf, labels, acc, ticket, out);
}

// Round 3
// 99.848 us; speedup vs baseline: 1.2980x; 1.2980x over previous
//
#include <hip/hip_runtime.h>
#include <math.h>

#define NB 8192
#define DK 256
#define BM 128
#define BK 64
#define NTILE 64                    // NB/BM
#define NBLK (NTILE*(NTILE+1)/2)    // 2080 upper-triangular tiles
#define NXCD 8
#define CPX (NBLK / NXCD)           // 260, exact

typedef __bf16 bf16x8 __attribute__((ext_vector_type(8)));
typedef float f32x4 __attribute__((ext_vector_type(4)));

__device__ inline unsigned short f2bf(float f) {
  unsigned u = __float_as_uint(f);
  u += 0x7fffu + ((u >> 16) & 1u);          // round-to-nearest-even
  return (unsigned short)(u >> 16);
}

__device__ inline void gld_lds16(const void* g, void* l) {
  __builtin_amdgcn_global_load_lds(
      (const __attribute__((address_space(1))) void*)g,
      (__attribute__((address_space(3))) void*)l, 16, 0, 0);
}

// ---------------- Kernel 1: L2-normalize rows, fp32 -> bf16
__global__ __launch_bounds__(256) void normalize_kernel(
    const float* __restrict__ emb, unsigned short* __restrict__ ebf) {
  int wave = threadIdx.x >> 6;
  int lane = threadIdx.x & 63;
  int row = blockIdx.x * 4 + wave;                  // one wave per row
  const float4* src = reinterpret_cast<const float4*>(emb + (size_t)row * DK) + lane;
  float4 v = *src;
  float ss = v.x * v.x + v.y * v.y + v.z * v.z + v.w * v.w;
  #pragma unroll
  for (int m = 1; m < 64; m <<= 1) ss += __shfl_xor(ss, m, 64);
  float inv = 1.0f / sqrtf(ss);
  ushort4 o;
  o.x = f2bf(v.x * inv);
  o.y = f2bf(v.y * inv);
  o.z = f2bf(v.z * inv);
  o.w = f2bf(v.w * inv);
  *reinterpret_cast<ushort4*>(ebf + (size_t)row * DK + lane * 4) = o;
}

// ---------------- Kernel 2: sim tiles via bf16 MFMA + fused epilogue
// R1 structure (single-buffer, 4 blocks/CU) + triangular 1D grid + XCD swizzle.
// NO atomics: each block plain-stores its partial sum to its own slot.
__global__ __launch_bounds__(256) void circle_gemm(
    const unsigned short* __restrict__ ebf, const int* __restrict__ labels,
    float* __restrict__ partial) {
  // bijective XCD-aware swizzle (T1, m204): consecutive triangular ids ->
  // same XCD => A-row-panel L2 reuse. 2080 % 8 == 0 so simple form is exact.
  int bid = (blockIdx.x % NXCD) * CPX + blockIdx.x / NXCD;

  // decode triangular tile index (uniform scalar loop, <=64 iters)
  int rem = bid;
  int tr = 0;
  while (rem >= NTILE - tr) { rem -= NTILE - tr; ++tr; }
  int tc = tr + rem;

  __shared__ unsigned short As[BM * BK];             // 16 KB, swizzled storage
  __shared__ unsigned short Bs[BM * BK];             // 16 KB
  __shared__ int labR[BM], labC[BM];
  __shared__ float wsum[4];

  int tid = threadIdx.x;
  int lane = tid & 63;
  int wave = tid >> 6;
  int row0 = tr * BM, col0 = tc * BM;

  if (tid < 128) labR[tid] = labels[row0 + tid];
  else           labC[tid - 128] = labels[col0 + (tid - 128)];

  f32x4 accf[4][4] = {};                             // 64 fp32 accum / thread
  int wr = (wave >> 1) * 64;                         // wave's 64x64 sub-tile
  int wc = (wave & 1) * 64;
  int frow = lane & 15;
  int khi = (lane >> 4) << 3;

  for (int k0 = 0; k0 < DK; k0 += BK) {
    // stage A,B: LDS dest linear, global source pre-swizzled (m173 pattern)
    #pragma unroll
    for (int q = 0; q < 4; ++q) {
      int o = q * 4096 + tid * 16;                   // linear byte offset
      int r = o >> 7;                                // row (128B rows)
      int os = o ^ ((r & 7) << 4);                   // swizzled (same row)
      int kc = (os & 127) >> 1;                      // bf16 col within row
      gld_lds16(&ebf[(size_t)(row0 + r) * DK + k0 + kc], ((char*)As) + o);
      gld_lds16(&ebf[(size_t)(col0 + r) * DK + k0 + kc], ((char*)Bs) + o);
    }
    __syncthreads();                                 // drain + all-arrived

    #pragma unroll
    for (int kk = 0; kk < BK; kk += 32) {
      int kb = (kk + khi) * 2;                       // byte offset of 8-k group
      bf16x8 a[4], b[4];
      #pragma unroll
      for (int m = 0; m < 4; ++m) {
        int r = wr + m * 16 + frow;
        int ob = ((r << 7) + kb) ^ ((r & 7) << 4);   // swizzled read
        a[m] = *reinterpret_cast<bf16x8*>(((char*)As) + ob);
      }
      #pragma unroll
      for (int n = 0; n < 4; ++n) {
        int r = wc + n * 16 + frow;
        int ob = ((r << 7) + kb) ^ ((r & 7) << 4);
        b[n] = *reinterpret_cast<bf16x8*>(((char*)Bs) + ob);
      }
      #pragma unroll
      for (int m = 0; m < 4; ++m)
        #pragma unroll
        for (int n = 0; n < 4; ++n)
          accf[m][n] = __builtin_amdgcn_mfma_f32_16x16x32_bf16(a[m], b[n], accf[m][n], 0, 0, 0);
    }
    __syncthreads();                                 // protect buffer reuse
  }

  // epilogue: circle-loss terms, one exp per element
  // C/D layout (verified m89/m91): col = lane&15, row = (lane>>4)*4 + reg
  float lsum = 0.0f;
  int rbase = wr + ((lane >> 4) << 2);
  int cbase = wc + (lane & 15);
  #pragma unroll
  for (int m = 0; m < 4; ++m) {
    #pragma unroll
    for (int n = 0; n < 4; ++n) {
      int lc = labC[cbase + n * 16];
      #pragma unroll
      for (int e = 0; e < 4; ++e) {
        float s = accf[m][n][e];
        bool pos = (labR[rbase + m * 16 + e] == lc);
        float relu = pos ? fmaxf(s - 0.75f, 0.0f) : fmaxf(0.25f - s, 0.0f);
        float arg  = pos ? (2.5f - 2.0f * s)      : (2.0f * s + 0.5f);
        lsum += relu * __expf(arg);
      }
    }
  }
  #pragma unroll
  for (int m = 32; m; m >>= 1) lsum += __shfl_xor(lsum, m, 64);
  if (lane == 0) wsum[wave] = lsum;
  __syncthreads();
  if (tid == 0) {
    float s = wsum[0] + wsum[1] + wsum[2] + wsum[3];
    if (tc != tr) s *= 2.0f;                         // symmetry doubling
    partial[bid] = s;                                // plain store, no atomic
  }
}

// ---------------- Kernel 3: reduce partials + log1p (one block)
__global__ __launch_bounds__(256) void finalize_kernel(
    const float* __restrict__ partial, float* __restrict__ out) {
  __shared__ float wsum[4];
  int tid = threadIdx.x;
  float s = 0.0f;
  for (int i = tid; i < NBLK; i += 256) s += partial[i];
  #pragma unroll
  for (int m = 32; m; m >>= 1) s += __shfl_xor(s, m, 64);
  if ((tid & 63) == 0) wsum[tid >> 6] = s;
  __syncthreads();
  if (tid == 0) out[0] = logf(1.0f + wsum[0] + wsum[1] + wsum[2] + wsum[3]);
}

extern "C" void kernel_launch(void* const* d_in, const int* in_sizes, int n_in,
                              void* d_out, int out_size, void* d_ws, size_t ws_size,
                              hipStream_t stream) {
  const float* emb = (const float*)d_in[0];
  const int* labels = (const int*)d_in[1];
  float* out = (float*)d_out;
  unsigned short* ebf = (unsigned short*)d_ws;                       // 4 MB bf16 E
  float* partial = (float*)((char*)d_ws + (size_t)NB * DK * 2);      // 2080 floats

  hipLaunchKernelGGL(normalize_kernel, dim3(NB / 4), dim3(256), 0, stream, emb, ebf);
  hipLaunchKernelGGL(circle_gemm, dim3(NBLK), dim3(256), 0, stream, ebf, labels, partial);
  hipLaunchKernelGGL(finalize_kernel, dim3(1), dim3(256), 0, stream, partial, out);
}